// Round 14
// baseline (1057.186 us; speedup 1.0000x reference)
//
#include <hip/hip_runtime.h>
#include <cstdint>

#define DEV __device__ __forceinline__

typedef __attribute__((ext_vector_type(8))) short bf16x8;
typedef __attribute__((ext_vector_type(4))) short bf16x4;
typedef __attribute__((ext_vector_type(4))) float f32x4;
typedef __attribute__((ext_vector_type(8))) unsigned short u16x8;

DEV float bf2f(unsigned short u) { return __uint_as_float(((unsigned)u) << 16); }
DEV unsigned short f2bf(float f) {
  unsigned u = __float_as_uint(f);
  u += 0x7FFFu + ((u >> 16) & 1u);
  return (unsigned short)(u >> 16);
}

DEV void gload_lds16(const void* g, void* lds) {
  __builtin_amdgcn_global_load_lds(
      (const __attribute__((address_space(1))) unsigned int*)g,
      (__attribute__((address_space(3))) unsigned int*)lds, 16, 0, 0);
}

// ---------------- prep mega-kernel ----------------
// [0,2048) embed | [2048,3072) dpb | rest: weight fp32 (K,N) -> bf16 tiled
// B^T tile layout: [nt][kt][128 n][64 k], XOR swizzle pre-applied (element
// (r,k) at short-offset r*64 + ((k>>3)^(r&7))*8 + (k&7)).
__global__ __launch_bounds__(256) void k_prep(
    const int* __restrict__ tokens, const float* __restrict__ tok_emb,
    const float* __restrict__ pos_emb, float* __restrict__ x,
    const float* __restrict__ w1, const float* __restrict__ b1,
    const float* __restrict__ w2, const float* __restrict__ b2,
    const float* __restrict__ w3, const float* __restrict__ b3,
    float* __restrict__ tableT,
    const float* __restrict__ Wqkv, unsigned short* __restrict__ WqkvT,
    const float* __restrict__ Wo, unsigned short* __restrict__ WoT,
    const float* __restrict__ Wff1, unsigned short* __restrict__ Wff1T,
    const float* __restrict__ Wff2, unsigned short* __restrict__ Wff2T,
    const float* __restrict__ Wlog, unsigned short* __restrict__ WlogT) {
  __shared__ unsigned short sm16[8192];  // 16KB: dst-tile image / dpb scratch
  int b = blockIdx.x, t = threadIdx.x;
  if (b < 2048) {  // ---- embed ----
    int tok = tokens[b];
    int c = t * 4;
    float4 a = *(const float4*)(tok_emb + (long)tok * 1024 + c);
    float4 p = *(const float4*)(pos_emb + (long)b * 1024 + c);
    float4 r;
    r.x = a.x + p.x; r.y = a.y + p.y; r.z = a.z + p.z; r.w = a.w + p.w;
    *(float4*)(x + (long)b * 1024 + c) = r;
    return;
  }
  b -= 2048;
  if (b < 1024) {  // ---- dpb: rel-position b; write tableT[h][1024] ----
    float* h1 = (float*)sm16;
    float* h2 = h1 + 512;
    float rf = (float)b;
    for (int c = t; c < 512; c += 256) {
      float v = rf * w1[c] + b1[c];
      h1[c] = v / (1.0f + __expf(-v));
    }
    __syncthreads();
    for (int c = t; c < 512; c += 256) {
      float acc = b2[c];
      for (int k2 = 0; k2 < 512; ++k2) acc = fmaf(h1[k2], w2[(long)k2 * 512 + c], acc);
      h2[c] = acc / (1.0f + __expf(-acc));
    }
    __syncthreads();
    if (t < 16) {
      float acc = b3[t];
      for (int k2 = 0; k2 < 512; ++k2) acc = fmaf(h2[k2], w3[k2 * 16 + t], acc);
      tableT[t * 1024 + b] = acc;
    }
    return;
  }
  b -= 1024;
  // ---- one dst tile (128 n x 64 k) per block ----
  const float* src; unsigned short* dst;
  int N, Kreal, nt, kt, mode;
  if (b < 1536) {  // qkv: 4 z x 24 nt x 16 kt
    int z = b / 384, r = b % 384;
    nt = r / 16; kt = r % 16; mode = 0; N = 3072; Kreal = 1024;
    src = Wqkv + (long)z * 1024 * 3072;
    dst = WqkvT + ((long)z * 384 + r) * 8192;
  } else if ((b -= 1536) < 512) {  // wo: 4 z x 8 x 16
    int z = b / 128, r = b % 128;
    nt = r / 16; kt = r % 16; mode = 0; N = 1024; Kreal = 1024;
    src = Wo + (long)z * 1024 * 1024;
    dst = WoT + ((long)z * 128 + r) * 8192;
  } else if ((b -= 512) < 2752) {  // ff1: 4 z x 43 x 16 (GLU interleave)
    int z = b / 688, r = b % 688;
    nt = r / 16; kt = r % 16; mode = 1; N = 5460; Kreal = 1024;
    src = Wff1 + (long)z * 1024 * 5460;
    dst = Wff1T + ((long)z * 688 + r) * 8192;
  } else if ((b -= 2752) < 1376) {  // ff2: 4 z x 8 x 43
    int z = b / 344, r = b % 344;
    nt = r / 43; kt = r % 43; mode = 0; N = 1024; Kreal = 2730;
    src = Wff2 + (long)z * 2730 * 1024;
    dst = Wff2T + ((long)z * 344 + r) * 8192;
  } else {  // wlog: 250 x 16
    b -= 1376;
    nt = b / 16; kt = b % 16; mode = 0; N = 32000; Kreal = 1024;
    src = Wlog;
    dst = WlogT + (long)b * 8192;
  }
  const int k0 = kt * 64;
  const int q = t & 31;   // n-quad: rows q*4 .. q*4+3
  const int kc = t >> 5;  // k-chunk: k = kc*8 + e
  u16x8 pa, pb, pc, pd;   // bf16 k-vectors for the 4 owned rows
  if (mode == 0) {
    const int nb = nt * 128 + q * 4;
    float4 v[8];
#pragma unroll
    for (int e = 0; e < 8; ++e) {
      int k = k0 + kc * 8 + e;
      int kcl = min(k, Kreal - 1);
      v[e] = *(const float4*)(src + (long)kcl * N + nb);
    }
    __builtin_amdgcn_sched_barrier(0);
#pragma unroll
    for (int e = 0; e < 8; ++e) {
      bool ok = (k0 + kc * 8 + e) < Kreal;
      pa[e] = ok ? f2bf(v[e].x) : (unsigned short)0;
      pb[e] = ok ? f2bf(v[e].y) : (unsigned short)0;
      pc[e] = ok ? f2bf(v[e].z) : (unsigned short)0;
      pd[e] = ok ? f2bf(v[e].w) : (unsigned short)0;
    }
  } else {
    const int f0 = nt * 64 + q * 2;
    const int f0c = min(f0, 2728);
    float2 av[8], gvv[8];
#pragma unroll
    for (int e = 0; e < 8; ++e) {
      const float* sr = src + (long)(k0 + kc * 8 + e) * 5460;
      av[e] = *(const float2*)(sr + f0c);
      gvv[e] = *(const float2*)(sr + 2730 + f0c);
    }
    __builtin_amdgcn_sched_barrier(0);
    const bool ok0 = f0 < 2730, ok1 = (f0 + 1) < 2730;
#pragma unroll
    for (int e = 0; e < 8; ++e) {
      pa[e] = ok0 ? f2bf(av[e].x) : (unsigned short)0;
      pb[e] = ok0 ? f2bf(gvv[e].x) : (unsigned short)0;
      pc[e] = ok1 ? f2bf(av[e].y) : (unsigned short)0;
      pd[e] = ok1 ? f2bf(gvv[e].y) : (unsigned short)0;
    }
  }
  {
    const int r0 = q * 4;
    *(u16x8*)&sm16[(r0 + 0) * 64 + ((kc ^ ((r0 + 0) & 7)) * 8)] = pa;
    *(u16x8*)&sm16[(r0 + 1) * 64 + ((kc ^ ((r0 + 1) & 7)) * 8)] = pb;
    *(u16x8*)&sm16[(r0 + 2) * 64 + ((kc ^ ((r0 + 2) & 7)) * 8)] = pc;
    *(u16x8*)&sm16[(r0 + 3) * 64 + ((kc ^ ((r0 + 3) & 7)) * 8)] = pd;
  }
  __syncthreads();
#pragma unroll
  for (int i2 = 0; i2 < 4; ++i2)
    *(u16x8*)(dst + i2 * 2048 + t * 8) = *(const u16x8*)&sm16[i2 * 2048 + t * 8];
}

// ---------------- layernorm: one wave per row, 4 rows/block ----------------
__global__ __launch_bounds__(256) void k_ln4(const float* __restrict__ x,
    const float* __restrict__ g, const float* __restrict__ b,
    unsigned short* __restrict__ out) {
  const int row = blockIdx.x * 4 + (threadIdx.x >> 6);
  const int l = threadIdx.x & 63;
  const float* xr = x + (long)row * 1024 + l * 16;
  float4 v[4];
#pragma unroll
  for (int e = 0; e < 4; ++e) v[e] = ((const float4*)xr)[e];
  float s = 0.0f;
#pragma unroll
  for (int e = 0; e < 4; ++e) s += v[e].x + v[e].y + v[e].z + v[e].w;
#pragma unroll
  for (int off = 32; off; off >>= 1) s += __shfl_xor(s, off);
  float mean = s * (1.0f / 1024.0f);
  float sq = 0.0f;
#pragma unroll
  for (int e = 0; e < 4; ++e) {
    float a0 = v[e].x - mean, a1 = v[e].y - mean, a2 = v[e].z - mean, a3 = v[e].w - mean;
    sq += a0 * a0 + a1 * a1 + a2 * a2 + a3 * a3;
  }
#pragma unroll
  for (int off = 32; off; off >>= 1) sq += __shfl_xor(sq, off);
  float inv = rsqrtf(sq * (1.0f / 1024.0f) + 1e-5f);
  const float* gr = g + l * 16;
  const float* br = b + l * 16;
  unsigned short* orow = out + (long)row * 1024 + l * 16;
#pragma unroll
  for (int e = 0; e < 4; ++e) {
    float4 gv = ((const float4*)gr)[e];
    float4 bv = ((const float4*)br)[e];
    ushort4 o;
    o.x = f2bf((v[e].x - mean) * inv * gv.x + bv.x);
    o.y = f2bf((v[e].y - mean) * inv * gv.y + bv.y);
    o.z = f2bf((v[e].z - mean) * inv * gv.z + bv.z);
    o.w = f2bf((v[e].w - mean) * inv * gv.w + bv.w);
    ((ushort4*)orow)[e] = o;
  }
}

// ---------------- MFMA flash local attention ----------------
__global__ __launch_bounds__(256, 2) void k_attn_mfma(
    const unsigned short* __restrict__ qkv, const float* __restrict__ tableT,
    unsigned short* __restrict__ o) {
  __shared__ unsigned short Ks[64 * 64];
  __shared__ unsigned short Vt[64 * 72];
  __shared__ unsigned short Ps[4][16 * 72];
  __shared__ float biasl[1024];
  const int qt = blockIdx.x, h = blockIdx.y, wi = blockIdx.z;
  const int iw0 = qt * 64;
  const int t = threadIdx.x;
  const int w = t >> 6, l = t & 63;
  const int lq = l & 15, lk = l >> 4;

  *(float4*)&biasl[t * 4] = *(const float4*)(tableT + h * 1024 + t * 4);

  const unsigned short* qp = qkv + (long)(wi * 512 + iw0 + w * 16 + lq) * 3072 + h * 64;
  bf16x8 qf0 = *(const bf16x8*)(qp + lk * 8);
  bf16x8 qf1 = *(const bf16x8*)(qp + 32 + lk * 8);

  f32x4 oacc[4] = {};
  float mrun[4] = {-3.0e38f, -3.0e38f, -3.0e38f, -3.0e38f};
  float srun[4] = {};

  const int kt0 = (wi == 0) ? 8 : qt;
  const int kt1 = qt + 8;
  for (int kt = kt0; kt <= kt1; ++kt) {
    const int ktbase = kt * 64;
    const long kgbase = (long)((wi - 1) * 512 + ktbase);
    __syncthreads();
    {
      const unsigned short* Kg = qkv + kgbase * 3072 + 1024 + h * 64;
#pragma unroll
      for (int s2 = 0; s2 < 2; ++s2) {
        int g = s2 * 4 + w;
        int row = g * 8 + (l >> 3);
        int gch = (l & 7) ^ (row & 7);
        gload_lds16(Kg + (long)row * 3072 + gch * 8, &Ks[g * 512]);
      }
    }
    {
      int kp = t & 31, dg = t >> 5;
      const unsigned short* Vg =
          qkv + (kgbase + 2 * kp) * 3072 + 2048 + h * 64 + dg * 8;
      bf16x8 a0 = *(const bf16x8*)Vg;
      bf16x8 a1 = *(const bf16x8*)(Vg + 3072);
#pragma unroll
      for (int e = 0; e < 8; ++e) {
        unsigned pack = ((unsigned)(unsigned short)a0[e]) |
                        (((unsigned)(unsigned short)a1[e]) << 16);
        *(unsigned*)&Vt[(dg * 8 + e) * 72 + 2 * kp] = pack;
      }
    }
    asm volatile("s_waitcnt vmcnt(0)" ::: "memory");
    __syncthreads();

    f32x4 sacc[4] = {};
#pragma unroll
    for (int ct = 0; ct < 4; ++ct) {
      int krow = ct * 16 + lq;
      bf16x8 kf0 = *(const bf16x8*)&Ks[krow * 64 + (((0 + lk) ^ (krow & 7)) * 8)];
      bf16x8 kf1 = *(const bf16x8*)&Ks[krow * 64 + (((4 + lk) ^ (krow & 7)) * 8)];
      sacc[ct] = __builtin_amdgcn_mfma_f32_16x16x32_bf16(qf0, kf0, sacc[ct], 0, 0, 0);
      sacc[ct] = __builtin_amdgcn_mfma_f32_16x16x32_bf16(qf1, kf1, sacc[ct], 0, 0, 0);
    }

#pragma unroll
    for (int r = 0; r < 4; ++r) {
      const int iw = iw0 + w * 16 + lk * 4 + r;
      float sc[4];
#pragma unroll
      for (int ct = 0; ct < 4; ++ct) {
        int jj = ktbase + ct * 16 + lq;
        int di = 512 + iw - jj;
        int dic = min(max(di, 0), 1023);
        bool allowed = (jj >= iw) && (jj <= iw + 512);
        float v = sacc[ct][r] * 0.125f + biasl[dic];
        sc[ct] = allowed ? v : -3.0e38f;
      }
      float mx = fmaxf(fmaxf(sc[0], sc[1]), fmaxf(sc[2], sc[3]));
      mx = fmaxf(mx, __shfl_xor(mx, 1));
      mx = fmaxf(mx, __shfl_xor(mx, 2));
      mx = fmaxf(mx, __shfl_xor(mx, 4));
      mx = fmaxf(mx, __shfl_xor(mx, 8));
      float mnew = fmaxf(mrun[r], mx);
      float f = __expf(mrun[r] - mnew);
      mrun[r] = mnew;
      float rs = 0.0f;
#pragma unroll
      for (int ct = 0; ct < 4; ++ct) {
        float pv = __expf(sc[ct] - mnew);
        rs += pv;
        Ps[w][(lk * 4 + r) * 72 + ct * 16 + lq] = f2bf(pv);
      }
      rs += __shfl_xor(rs, 1);
      rs += __shfl_xor(rs, 2);
      rs += __shfl_xor(rs, 4);
      rs += __shfl_xor(rs, 8);
      srun[r] = srun[r] * f + rs;
#pragma unroll
      for (int dt = 0; dt < 4; ++dt) oacc[dt][r] *= f;
    }
    asm volatile("s_waitcnt lgkmcnt(0)" ::: "memory");

#pragma unroll
    for (int ks = 0; ks < 2; ++ks) {
      bf16x4 pa0 = *(const bf16x4*)&Ps[w][lq * 72 + ks * 32 + lk * 8];
      bf16x4 pa1 = *(const bf16x4*)&Ps[w][lq * 72 + ks * 32 + lk * 8 + 4];
      bf16x8 pa = __builtin_shufflevector(pa0, pa1, 0, 1, 2, 3, 4, 5, 6, 7);
#pragma unroll
      for (int dt = 0; dt < 4; ++dt) {
        int drow = dt * 16 + lq;
        bf16x4 vb0 = *(const bf16x4*)&Vt[drow * 72 + ks * 32 + lk * 8];
        bf16x4 vb1 = *(const bf16x4*)&Vt[drow * 72 + ks * 32 + lk * 8 + 4];
        bf16x8 vb = __builtin_shufflevector(vb0, vb1, 0, 1, 2, 3, 4, 5, 6, 7);
        oacc[dt] = __builtin_amdgcn_mfma_f32_16x16x32_bf16(pa, vb, oacc[dt], 0, 0, 0);
      }
    }
  }

  unsigned short* ob =
      o + (long)(wi * 512 + iw0 + w * 16 + lk * 4) * 1024 + h * 64 + lq;
#pragma unroll
  for (int r = 0; r < 4; ++r) {
    float inv = 1.0f / srun[r];
#pragma unroll
    for (int dt = 0; dt < 4; ++dt)
      ob[(long)r * 1024 + dt * 16] = f2bf(oacc[dt][r] * inv);
  }
}

// ---------------- GEMM: C(M,N) = A(M,K) * B^T, B in tiled layout ----------
// B: [nt][kt][128][64] swizzle-pre-applied tiles -> staging = linear copy.
// 1D grid, bm-fast + bijective XCD swizzle.
// PIPE=0: proven single-buffer 2-barrier loop.
// PIPE=1: asymmetric pipeline — B double-buffered (issued BEFORE the MFMA
//   phase, latency hides under compute), A single-buffered (L2-resident,
//   restaged between raw barriers). LDS 48KB -> still 3 blocks/CU.
// EPI: 0 = store bf16, 1 = fp32 +=, 2 = store fp32, 3 = fused GLU
template <int EPI, int BM, int PIPE>
__global__ __launch_bounds__(256, 2) void k_gemm(const unsigned short* __restrict__ A,
    const unsigned short* __restrict__ BTt, void* __restrict__ Cout,
    int N, int K, int nbm) {
  constexpr int MI = BM / 32;
  constexpr int NBUF = PIPE ? 2 : 1;
  __shared__ unsigned short As[BM * 64];
  __shared__ unsigned short Bs[NBUF][128 * 64];
  const int nwg = gridDim.x;
  const int orig = blockIdx.x;
  const int q8 = nwg >> 3, r8 = nwg & 7;
  const int xcd = orig & 7, i8 = orig >> 3;
  const int wgid = (xcd < r8 ? xcd * (q8 + 1) : r8 * (q8 + 1) + (xcd - r8) * q8) + i8;
  const int bm = wgid % nbm;
  const int bn = wgid / nbm;
  const int t = threadIdx.x;
  const int w = t >> 6, l = t & 63;
  const int wm = w >> 1, wn = w & 1;
  const int lrow = l >> 3, lch = l & 7;
  const int lq = l & 15, lk = l >> 4;
  f32x4 acc[MI][4] = {};
  const long arow0 = (long)bm * BM;
  const int NT = K >> 6;
  const unsigned short* btile = BTt + (long)bn * NT * 8192;
  const int gch = lch ^ lrow;

  auto STAGE_B = [&](int buf, int kt) {
    const unsigned short* bsrc = btile + (long)kt * 8192 + l * 8;
#pragma unroll
    for (int s2 = 0; s2 < 4; ++s2) {
      int grp = s2 * 4 + w;
      gload_lds16(bsrc + grp * 512, &Bs[buf][grp * 512]);
    }
  };
  auto STAGE_A = [&](int kt) {
#pragma unroll
    for (int s2 = 0; s2 < MI; ++s2) {
      int grp = s2 * 4 + w;
      int r = grp * 8 + lrow;
      gload_lds16(A + (arow0 + r) * K + kt * 64 + gch * 8, &As[grp * 512]);
    }
  };

  if (PIPE) {
    STAGE_B(0, 0);
    STAGE_A(0);
    asm volatile("s_waitcnt vmcnt(0)" ::: "memory");
    asm volatile("s_barrier" ::: "memory");
  }
  for (int kt = 0; kt < NT; ++kt) {
    const int cur = PIPE ? (kt & 1) : 0;
    if (PIPE) {
      if (kt + 1 < NT) STAGE_B(cur ^ 1, kt + 1);  // flies under MFMA below
    } else {
      __syncthreads();
      STAGE_B(0, kt);
      STAGE_A(kt);
      asm volatile("s_waitcnt vmcnt(0)" ::: "memory");
      __syncthreads();
    }
#pragma unroll
    for (int kk = 0; kk < 2; ++kk) {
      bf16x8 af[MI], bfr[4];
#pragma unroll
      for (int i = 0; i < MI; ++i) {
        int ra = wm * (BM / 2) + i * 16 + lq;
        af[i] = *(const bf16x8*)&As[ra * 64 + (((kk * 4 + lk) ^ (ra & 7)) * 8)];
      }
#pragma unroll
      for (int j = 0; j < 4; ++j) {
        int rb = wn * 64 + j * 16 + lq;
        bfr[j] = *(const bf16x8*)&Bs[cur][rb * 64 + (((kk * 4 + lk) ^ (rb & 7)) * 8)];
      }
#pragma unroll
      for (int i = 0; i < MI; ++i)
#pragma unroll
        for (int j = 0; j < 4; ++j)
          acc[i][j] = __builtin_amdgcn_mfma_f32_16x16x32_bf16(af[i], bfr[j],
                                                              acc[i][j], 0, 0, 0);
    }
    if (PIPE && kt + 1 < NT) {
      asm volatile("s_barrier" ::: "memory");  // all waves done reading As/Bs[cur]
      STAGE_A(kt + 1);
      asm volatile("s_waitcnt vmcnt(0)" ::: "memory");  // own A+B loads drained
      asm volatile("s_barrier" ::: "memory");           // all LDS writes visible
    }
  }
  const int rbase = bm * BM + wm * (BM / 2) + lk * 4;
  const int cbase = bn * 128 + wn * 64 + lq;
#pragma unroll
  for (int i = 0; i < MI; ++i) {
#pragma unroll
    for (int j = 0; j < 4; ++j) {
#pragma unroll
      for (int r2 = 0; r2 < 4; ++r2) {
        long row = rbase + i * 16 + r2;
        long col = cbase + j * 16;
        float v = acc[i][j][r2];
        if (EPI == 0) {
          ((unsigned short*)Cout)[row * N + col] = f2bf(v);
        } else if (EPI == 1) {
          ((float*)Cout)[row * N + col] += v;
        } else if (EPI == 2) {
          ((float*)Cout)[row * N + col] = v;
        } else {
          float gpart = __shfl_xor(v, 1);
          if ((lq & 1) == 0) {
            float uval =
                v * (0.5f * gpart * (1.0f + erff(gpart * 0.70710678118654752f)));
            ((unsigned short*)Cout)[row * (N >> 1) + (col >> 1)] = f2bf(uval);
          }
        }
      }
    }
  }
}

extern "C" void kernel_launch(void* const* d_in, const int* in_sizes, int n_in,
                              void* d_out, int out_size, void* d_ws, size_t ws_size,
                              hipStream_t stream) {
  (void)in_sizes; (void)n_in; (void)out_size; (void)ws_size;
  const int* tokens   = (const int*)d_in[0];
  const float* tok_emb = (const float*)d_in[1];
  const float* pos_emb = (const float*)d_in[2];
  const float* dpb_w1 = (const float*)d_in[3];
  const float* dpb_b1 = (const float*)d_in[4];
  const float* dpb_w2 = (const float*)d_in[5];
  const float* dpb_b2 = (const float*)d_in[6];
  const float* dpb_w3 = (const float*)d_in[7];
  const float* dpb_b3 = (const float*)d_in[8];
  const float* ln1_g  = (const float*)d_in[9];
  const float* ln1_b  = (const float*)d_in[10];
  const float* Wqkv   = (const float*)d_in[11];
  const float* Wo     = (const float*)d_in[12];
  const float* ln2_g  = (const float*)d_in[13];
  const float* ln2_b  = (const float*)d_in[14];
  const float* Wff1   = (const float*)d_in[15];
  const float* Wff2   = (const float*)d_in[16];
  const float* lnf_g  = (const float*)d_in[17];
  const float* lnf_b  = (const float*)d_in[18];
  const float* Wlog   = (const float*)d_in[19];
  float* out = (float*)d_out;

  char* p = (char*)d_ws;
  auto carve = [&](size_t bytes) {
    char* q = p;
    p += (bytes + 255) & ~(size_t)255;
    return (void*)q;
  };
  unsigned short* WqkvT = (unsigned short*)carve((size_t)4 * 3072 * 1024 * 2);
  unsigned short* WoT   = (unsigned short*)carve((size_t)4 * 1024 * 1024 * 2);
  unsigned short* Wff1T = (unsigned short*)carve((size_t)4 * 5504 * 1024 * 2);
  unsigned short* Wff2T = (unsigned short*)carve((size_t)4 * 1024 * 2752 * 2);
  unsigned short* WlogT = (unsigned short*)carve((size_t)32000 * 1024 * 2);
  float*          x     = (float*)carve((size_t)2048 * 1024 * 4);
  unsigned short* hbuf  = (unsigned short*)carve((size_t)2048 * 1024 * 2);
  unsigned short* qkv   = (unsigned short*)carve((size_t)2048 * 3072 * 2);
  unsigned short* ao    = (unsigned short*)carve((size_t)2048 * 1024 * 2);
  unsigned short* ubuf  = (unsigned short*)carve((size_t)2048 * 2752 * 2);
  float*          tableT = (float*)carve((size_t)16 * 1024 * 4);

  // prep: embed(2048) + dpb(1024) + tiles(10176) = 13248 blocks
  k_prep<<<13248, 256, 0, stream>>>(
      tokens, tok_emb, pos_emb, x, dpb_w1, dpb_b1, dpb_w2, dpb_b2, dpb_w3,
      dpb_b3, tableT, Wqkv, WqkvT, Wo, WoT, Wff1, Wff1T, Wff2, Wff2T, Wlog, WlogT);

  for (int l = 0; l < 4; ++l) {
    k_ln4<<<512, 256, 0, stream>>>(x, ln1_g + l * 1024, ln1_b + l * 1024, hbuf);
    k_gemm<0, 64, 0><<<dim3(32 * (3072 / 128)), 256, 0, stream>>>(
        hbuf, WqkvT + (long)l * 3072 * 1024, qkv, 3072, 1024, 32);
    k_attn_mfma<<<dim3(8, 16, 4), 256, 0, stream>>>(qkv, tableT, ao);
    k_gemm<1, 64, 0><<<dim3(32 * (1024 / 128)), 256, 0, stream>>>(
        ao, WoT + (long)l * 1024 * 1024, x, 1024, 1024, 32);
    k_ln4<<<512, 256, 0, stream>>>(x, ln2_g + l * 1024, ln2_b + l * 1024, hbuf);
    k_gemm<3, 128, 1><<<dim3(16 * (5504 / 128)), 256, 0, stream>>>(
        hbuf, Wff1T + (long)l * 5504 * 1024, ubuf, 5504, 1024, 16);
    k_gemm<1, 64, 0><<<dim3(32 * (1024 / 128)), 256, 0, stream>>>(
        ubuf, Wff2T + (long)l * 1024 * 2752, x, 1024, 2752, 32);
  }
  k_ln4<<<512, 256, 0, stream>>>(x, lnf_g, lnf_b, hbuf);
  k_gemm<2, 128, 1><<<dim3(16 * (32000 / 128)), 256, 0, stream>>>(
      hbuf, WlogT, out, 32000, 1024, 16);
}

// Round 15
// 1027.684 us; speedup vs baseline: 1.0287x; 1.0287x over previous
//
#include <hip/hip_runtime.h>
#include <cstdint>

#define DEV __device__ __forceinline__

typedef __attribute__((ext_vector_type(8))) short bf16x8;
typedef __attribute__((ext_vector_type(4))) short bf16x4;
typedef __attribute__((ext_vector_type(4))) float f32x4;
typedef __attribute__((ext_vector_type(8))) unsigned short u16x8;

DEV float bf2f(unsigned short u) { return __uint_as_float(((unsigned)u) << 16); }
DEV unsigned short f2bf(float f) {
  unsigned u = __float_as_uint(f);
  u += 0x7FFFu + ((u >> 16) & 1u);
  return (unsigned short)(u >> 16);
}

DEV void gload_lds16(const void* g, void* lds) {
  __builtin_amdgcn_global_load_lds(
      (const __attribute__((address_space(1))) unsigned int*)g,
      (__attribute__((address_space(3))) unsigned int*)lds, 16, 0, 0);
}

// ---------------- prep mega-kernel ----------------
// [0,2048) embed | [2048,3072) dpb | rest: weight fp32 (K,N) -> bf16 tiled
// B^T tile layout: [nt][kt][128 n][64 k], XOR swizzle pre-applied (element
// (r,k) at short-offset r*64 + ((k>>3)^(r&7))*8 + (k&7)).
__global__ __launch_bounds__(256) void k_prep(
    const int* __restrict__ tokens, const float* __restrict__ tok_emb,
    const float* __restrict__ pos_emb, float* __restrict__ x,
    const float* __restrict__ w1, const float* __restrict__ b1,
    const float* __restrict__ w2, const float* __restrict__ b2,
    const float* __restrict__ w3, const float* __restrict__ b3,
    float* __restrict__ tableT,
    const float* __restrict__ Wqkv, unsigned short* __restrict__ WqkvT,
    const float* __restrict__ Wo, unsigned short* __restrict__ WoT,
    const float* __restrict__ Wff1, unsigned short* __restrict__ Wff1T,
    const float* __restrict__ Wff2, unsigned short* __restrict__ Wff2T,
    const float* __restrict__ Wlog, unsigned short* __restrict__ WlogT) {
  __shared__ unsigned short sm16[8192];  // 16KB: dst-tile image / dpb scratch
  int b = blockIdx.x, t = threadIdx.x;
  if (b < 2048) {  // ---- embed ----
    int tok = tokens[b];
    int c = t * 4;
    float4 a = *(const float4*)(tok_emb + (long)tok * 1024 + c);
    float4 p = *(const float4*)(pos_emb + (long)b * 1024 + c);
    float4 r;
    r.x = a.x + p.x; r.y = a.y + p.y; r.z = a.z + p.z; r.w = a.w + p.w;
    *(float4*)(x + (long)b * 1024 + c) = r;
    return;
  }
  b -= 2048;
  if (b < 1024) {  // ---- dpb: rel-position b; write tableT[h][1024] ----
    float* h1 = (float*)sm16;
    float* h2 = h1 + 512;
    float rf = (float)b;
    for (int c = t; c < 512; c += 256) {
      float v = rf * w1[c] + b1[c];
      h1[c] = v / (1.0f + __expf(-v));
    }
    __syncthreads();
    for (int c = t; c < 512; c += 256) {
      float acc = b2[c];
      for (int k2 = 0; k2 < 512; ++k2) acc = fmaf(h1[k2], w2[(long)k2 * 512 + c], acc);
      h2[c] = acc / (1.0f + __expf(-acc));
    }
    __syncthreads();
    if (t < 16) {
      float acc = b3[t];
      for (int k2 = 0; k2 < 512; ++k2) acc = fmaf(h2[k2], w3[k2 * 16 + t], acc);
      tableT[t * 1024 + b] = acc;
    }
    return;
  }
  b -= 1024;
  // ---- one dst tile (128 n x 64 k) per block ----
  const float* src; unsigned short* dst;
  int N, Kreal, nt, kt, mode;
  if (b < 1536) {  // qkv: 4 z x 24 nt x 16 kt
    int z = b / 384, r = b % 384;
    nt = r / 16; kt = r % 16; mode = 0; N = 3072; Kreal = 1024;
    src = Wqkv + (long)z * 1024 * 3072;
    dst = WqkvT + ((long)z * 384 + r) * 8192;
  } else if ((b -= 1536) < 512) {  // wo: 4 z x 8 x 16
    int z = b / 128, r = b % 128;
    nt = r / 16; kt = r % 16; mode = 0; N = 1024; Kreal = 1024;
    src = Wo + (long)z * 1024 * 1024;
    dst = WoT + ((long)z * 128 + r) * 8192;
  } else if ((b -= 512) < 2752) {  // ff1: 4 z x 43 x 16 (GLU interleave)
    int z = b / 688, r = b % 688;
    nt = r / 16; kt = r % 16; mode = 1; N = 5460; Kreal = 1024;
    src = Wff1 + (long)z * 1024 * 5460;
    dst = Wff1T + ((long)z * 688 + r) * 8192;
  } else if ((b -= 2752) < 1376) {  // ff2: 4 z x 8 x 43
    int z = b / 344, r = b % 344;
    nt = r / 43; kt = r % 43; mode = 0; N = 1024; Kreal = 2730;
    src = Wff2 + (long)z * 2730 * 1024;
    dst = Wff2T + ((long)z * 344 + r) * 8192;
  } else {  // wlog: 250 x 16
    b -= 1376;
    nt = b / 16; kt = b % 16; mode = 0; N = 32000; Kreal = 1024;
    src = Wlog;
    dst = WlogT + (long)b * 8192;
  }
  const int k0 = kt * 64;
  const int q = t & 31;   // n-quad: rows q*4 .. q*4+3
  const int kc = t >> 5;  // k-chunk: k = kc*8 + e
  u16x8 pa, pb, pc, pd;   // bf16 k-vectors for the 4 owned rows
  if (mode == 0) {
    const int nb = nt * 128 + q * 4;
    float4 v[8];
#pragma unroll
    for (int e = 0; e < 8; ++e) {
      int k = k0 + kc * 8 + e;
      int kcl = min(k, Kreal - 1);
      v[e] = *(const float4*)(src + (long)kcl * N + nb);
    }
    __builtin_amdgcn_sched_barrier(0);
#pragma unroll
    for (int e = 0; e < 8; ++e) {
      bool ok = (k0 + kc * 8 + e) < Kreal;
      pa[e] = ok ? f2bf(v[e].x) : (unsigned short)0;
      pb[e] = ok ? f2bf(v[e].y) : (unsigned short)0;
      pc[e] = ok ? f2bf(v[e].z) : (unsigned short)0;
      pd[e] = ok ? f2bf(v[e].w) : (unsigned short)0;
    }
  } else {
    const int f0 = nt * 64 + q * 2;
    const int f0c = min(f0, 2728);
    float2 av[8], gvv[8];
#pragma unroll
    for (int e = 0; e < 8; ++e) {
      const float* sr = src + (long)(k0 + kc * 8 + e) * 5460;
      av[e] = *(const float2*)(sr + f0c);
      gvv[e] = *(const float2*)(sr + 2730 + f0c);
    }
    __builtin_amdgcn_sched_barrier(0);
    const bool ok0 = f0 < 2730, ok1 = (f0 + 1) < 2730;
#pragma unroll
    for (int e = 0; e < 8; ++e) {
      pa[e] = ok0 ? f2bf(av[e].x) : (unsigned short)0;
      pb[e] = ok0 ? f2bf(gvv[e].x) : (unsigned short)0;
      pc[e] = ok1 ? f2bf(av[e].y) : (unsigned short)0;
      pd[e] = ok1 ? f2bf(gvv[e].y) : (unsigned short)0;
    }
  }
  {
    const int r0 = q * 4;
    *(u16x8*)&sm16[(r0 + 0) * 64 + ((kc ^ ((r0 + 0) & 7)) * 8)] = pa;
    *(u16x8*)&sm16[(r0 + 1) * 64 + ((kc ^ ((r0 + 1) & 7)) * 8)] = pb;
    *(u16x8*)&sm16[(r0 + 2) * 64 + ((kc ^ ((r0 + 2) & 7)) * 8)] = pc;
    *(u16x8*)&sm16[(r0 + 3) * 64 + ((kc ^ ((r0 + 3) & 7)) * 8)] = pd;
  }
  __syncthreads();
#pragma unroll
  for (int i2 = 0; i2 < 4; ++i2)
    *(u16x8*)(dst + i2 * 2048 + t * 8) = *(const u16x8*)&sm16[i2 * 2048 + t * 8];
}

// ---------------- layernorm: one wave per row, 4 rows/block ----------------
__global__ __launch_bounds__(256) void k_ln4(const float* __restrict__ x,
    const float* __restrict__ g, const float* __restrict__ b,
    unsigned short* __restrict__ out) {
  const int row = blockIdx.x * 4 + (threadIdx.x >> 6);
  const int l = threadIdx.x & 63;
  const float* xr = x + (long)row * 1024 + l * 16;
  float4 v[4];
#pragma unroll
  for (int e = 0; e < 4; ++e) v[e] = ((const float4*)xr)[e];
  float s = 0.0f;
#pragma unroll
  for (int e = 0; e < 4; ++e) s += v[e].x + v[e].y + v[e].z + v[e].w;
#pragma unroll
  for (int off = 32; off; off >>= 1) s += __shfl_xor(s, off);
  float mean = s * (1.0f / 1024.0f);
  float sq = 0.0f;
#pragma unroll
  for (int e = 0; e < 4; ++e) {
    float a0 = v[e].x - mean, a1 = v[e].y - mean, a2 = v[e].z - mean, a3 = v[e].w - mean;
    sq += a0 * a0 + a1 * a1 + a2 * a2 + a3 * a3;
  }
#pragma unroll
  for (int off = 32; off; off >>= 1) sq += __shfl_xor(sq, off);
  float inv = rsqrtf(sq * (1.0f / 1024.0f) + 1e-5f);
  const float* gr = g + l * 16;
  const float* br = b + l * 16;
  unsigned short* orow = out + (long)row * 1024 + l * 16;
#pragma unroll
  for (int e = 0; e < 4; ++e) {
    float4 gv = ((const float4*)gr)[e];
    float4 bv = ((const float4*)br)[e];
    ushort4 o;
    o.x = f2bf((v[e].x - mean) * inv * gv.x + bv.x);
    o.y = f2bf((v[e].y - mean) * inv * gv.y + bv.y);
    o.z = f2bf((v[e].z - mean) * inv * gv.z + bv.z);
    o.w = f2bf((v[e].w - mean) * inv * gv.w + bv.w);
    ((ushort4*)orow)[e] = o;
  }
}

// ---------------- MFMA flash local attention ----------------
__global__ __launch_bounds__(256, 2) void k_attn_mfma(
    const unsigned short* __restrict__ qkv, const float* __restrict__ tableT,
    unsigned short* __restrict__ o) {
  __shared__ unsigned short Ks[64 * 64];
  __shared__ unsigned short Vt[64 * 72];
  __shared__ unsigned short Ps[4][16 * 72];
  __shared__ float biasl[1024];
  const int qt = blockIdx.x, h = blockIdx.y, wi = blockIdx.z;
  const int iw0 = qt * 64;
  const int t = threadIdx.x;
  const int w = t >> 6, l = t & 63;
  const int lq = l & 15, lk = l >> 4;

  *(float4*)&biasl[t * 4] = *(const float4*)(tableT + h * 1024 + t * 4);

  const unsigned short* qp = qkv + (long)(wi * 512 + iw0 + w * 16 + lq) * 3072 + h * 64;
  bf16x8 qf0 = *(const bf16x8*)(qp + lk * 8);
  bf16x8 qf1 = *(const bf16x8*)(qp + 32 + lk * 8);

  f32x4 oacc[4] = {};
  float mrun[4] = {-3.0e38f, -3.0e38f, -3.0e38f, -3.0e38f};
  float srun[4] = {};

  const int kt0 = (wi == 0) ? 8 : qt;
  const int kt1 = qt + 8;
  for (int kt = kt0; kt <= kt1; ++kt) {
    const int ktbase = kt * 64;
    const long kgbase = (long)((wi - 1) * 512 + ktbase);
    __syncthreads();
    {
      const unsigned short* Kg = qkv + kgbase * 3072 + 1024 + h * 64;
#pragma unroll
      for (int s2 = 0; s2 < 2; ++s2) {
        int g = s2 * 4 + w;
        int row = g * 8 + (l >> 3);
        int gch = (l & 7) ^ (row & 7);
        gload_lds16(Kg + (long)row * 3072 + gch * 8, &Ks[g * 512]);
      }
    }
    {
      int kp = t & 31, dg = t >> 5;
      const unsigned short* Vg =
          qkv + (kgbase + 2 * kp) * 3072 + 2048 + h * 64 + dg * 8;
      bf16x8 a0 = *(const bf16x8*)Vg;
      bf16x8 a1 = *(const bf16x8*)(Vg + 3072);
#pragma unroll
      for (int e = 0; e < 8; ++e) {
        unsigned pack = ((unsigned)(unsigned short)a0[e]) |
                        (((unsigned)(unsigned short)a1[e]) << 16);
        *(unsigned*)&Vt[(dg * 8 + e) * 72 + 2 * kp] = pack;
      }
    }
    asm volatile("s_waitcnt vmcnt(0)" ::: "memory");
    __syncthreads();

    f32x4 sacc[4] = {};
#pragma unroll
    for (int ct = 0; ct < 4; ++ct) {
      int krow = ct * 16 + lq;
      bf16x8 kf0 = *(const bf16x8*)&Ks[krow * 64 + (((0 + lk) ^ (krow & 7)) * 8)];
      bf16x8 kf1 = *(const bf16x8*)&Ks[krow * 64 + (((4 + lk) ^ (krow & 7)) * 8)];
      sacc[ct] = __builtin_amdgcn_mfma_f32_16x16x32_bf16(qf0, kf0, sacc[ct], 0, 0, 0);
      sacc[ct] = __builtin_amdgcn_mfma_f32_16x16x32_bf16(qf1, kf1, sacc[ct], 0, 0, 0);
    }

#pragma unroll
    for (int r = 0; r < 4; ++r) {
      const int iw = iw0 + w * 16 + lk * 4 + r;
      float sc[4];
#pragma unroll
      for (int ct = 0; ct < 4; ++ct) {
        int jj = ktbase + ct * 16 + lq;
        int di = 512 + iw - jj;
        int dic = min(max(di, 0), 1023);
        bool allowed = (jj >= iw) && (jj <= iw + 512);
        float v = sacc[ct][r] * 0.125f + biasl[dic];
        sc[ct] = allowed ? v : -3.0e38f;
      }
      float mx = fmaxf(fmaxf(sc[0], sc[1]), fmaxf(sc[2], sc[3]));
      mx = fmaxf(mx, __shfl_xor(mx, 1));
      mx = fmaxf(mx, __shfl_xor(mx, 2));
      mx = fmaxf(mx, __shfl_xor(mx, 4));
      mx = fmaxf(mx, __shfl_xor(mx, 8));
      float mnew = fmaxf(mrun[r], mx);
      float f = __expf(mrun[r] - mnew);
      mrun[r] = mnew;
      float rs = 0.0f;
#pragma unroll
      for (int ct = 0; ct < 4; ++ct) {
        float pv = __expf(sc[ct] - mnew);
        rs += pv;
        Ps[w][(lk * 4 + r) * 72 + ct * 16 + lq] = f2bf(pv);
      }
      rs += __shfl_xor(rs, 1);
      rs += __shfl_xor(rs, 2);
      rs += __shfl_xor(rs, 4);
      rs += __shfl_xor(rs, 8);
      srun[r] = srun[r] * f + rs;
#pragma unroll
      for (int dt = 0; dt < 4; ++dt) oacc[dt][r] *= f;
    }
    asm volatile("s_waitcnt lgkmcnt(0)" ::: "memory");

#pragma unroll
    for (int ks = 0; ks < 2; ++ks) {
      bf16x4 pa0 = *(const bf16x4*)&Ps[w][lq * 72 + ks * 32 + lk * 8];
      bf16x4 pa1 = *(const bf16x4*)&Ps[w][lq * 72 + ks * 32 + lk * 8 + 4];
      bf16x8 pa = __builtin_shufflevector(pa0, pa1, 0, 1, 2, 3, 4, 5, 6, 7);
#pragma unroll
      for (int dt = 0; dt < 4; ++dt) {
        int drow = dt * 16 + lq;
        bf16x4 vb0 = *(const bf16x4*)&Vt[drow * 72 + ks * 32 + lk * 8];
        bf16x4 vb1 = *(const bf16x4*)&Vt[drow * 72 + ks * 32 + lk * 8 + 4];
        bf16x8 vb = __builtin_shufflevector(vb0, vb1, 0, 1, 2, 3, 4, 5, 6, 7);
        oacc[dt] = __builtin_amdgcn_mfma_f32_16x16x32_bf16(pa, vb, oacc[dt], 0, 0, 0);
      }
    }
  }

  unsigned short* ob =
      o + (long)(wi * 512 + iw0 + w * 16 + lk * 4) * 1024 + h * 64 + lq;
#pragma unroll
  for (int r = 0; r < 4; ++r) {
    float inv = 1.0f / srun[r];
#pragma unroll
    for (int dt = 0; dt < 4; ++dt)
      ob[(long)r * 1024 + dt * 16] = f2bf(oacc[dt][r] * inv);
  }
}

// ---------------- GEMM: C(M,N) = A(M,K) * B^T, B in tiled layout ----------
// Single-buffer (r8 structure — 3 blocks/CU wave-overlap beats explicit dbuf;
// r9/r12/r14 pipeline variants all regressed via occupancy loss).
// B: [nt][kt][128][64] swizzle-pre-applied tiles -> staging = linear copy.
// 1D grid, bm-fast + bijective XCD swizzle.
// EPI: 0 = store bf16, 1 = fp32 +=, 2 = store fp32, 3 = fused GLU
template <int EPI, int BM>
__global__ __launch_bounds__(256, 2) void k_gemm(const unsigned short* __restrict__ A,
    const unsigned short* __restrict__ BTt, void* __restrict__ Cout,
    int N, int K, int nbm) {
  constexpr int MI = BM / 32;
  __shared__ unsigned short As[BM * 64];
  __shared__ unsigned short Bs[128 * 64];
  const int nwg = gridDim.x;
  const int orig = blockIdx.x;
  const int q8 = nwg >> 3, r8 = nwg & 7;
  const int xcd = orig & 7, i8 = orig >> 3;
  const int wgid = (xcd < r8 ? xcd * (q8 + 1) : r8 * (q8 + 1) + (xcd - r8) * q8) + i8;
  const int bm = wgid % nbm;
  const int bn = wgid / nbm;
  const int t = threadIdx.x;
  const int w = t >> 6, l = t & 63;
  const int wm = w >> 1, wn = w & 1;
  const int lrow = l >> 3, lch = l & 7;
  const int lq = l & 15, lk = l >> 4;
  f32x4 acc[MI][4] = {};
  const long arow0 = (long)bm * BM;
  const unsigned short* btile = BTt + (long)bn * (K >> 6) * 8192;
  for (int kt = 0; kt < K; kt += 64) {
    __syncthreads();
    const unsigned short* bsrc = btile + (long)(kt >> 6) * 8192 + l * 8;
#pragma unroll
    for (int s2 = 0; s2 < 4; ++s2) {
      int grp = s2 * 4 + w;
      gload_lds16(bsrc + grp * 512, &Bs[grp * 512]);
      if (s2 < MI) {
        int r = grp * 8 + lrow;
        int gch = lch ^ lrow;
        gload_lds16(A + (arow0 + r) * K + kt + gch * 8, &As[grp * 512]);
      }
    }
    asm volatile("s_waitcnt vmcnt(0)" ::: "memory");
    __syncthreads();
#pragma unroll
    for (int kk = 0; kk < 2; ++kk) {
      bf16x8 af[MI], bfr[4];
#pragma unroll
      for (int i = 0; i < MI; ++i) {
        int ra = wm * (BM / 2) + i * 16 + lq;
        af[i] = *(const bf16x8*)&As[ra * 64 + (((kk * 4 + lk) ^ (ra & 7)) * 8)];
      }
#pragma unroll
      for (int j = 0; j < 4; ++j) {
        int rb = wn * 64 + j * 16 + lq;
        bfr[j] = *(const bf16x8*)&Bs[rb * 64 + (((kk * 4 + lk) ^ (rb & 7)) * 8)];
      }
#pragma unroll
      for (int i = 0; i < MI; ++i)
#pragma unroll
        for (int j = 0; j < 4; ++j)
          acc[i][j] = __builtin_amdgcn_mfma_f32_16x16x32_bf16(af[i], bfr[j],
                                                              acc[i][j], 0, 0, 0);
    }
  }
  const int rbase = bm * BM + wm * (BM / 2) + lk * 4;
  const int cbase = bn * 128 + wn * 64 + lq;
#pragma unroll
  for (int i = 0; i < MI; ++i) {
#pragma unroll
    for (int j = 0; j < 4; ++j) {
#pragma unroll
      for (int r2 = 0; r2 < 4; ++r2) {
        long row = rbase + i * 16 + r2;
        long col = cbase + j * 16;
        float v = acc[i][j][r2];
        if (EPI == 0) {
          ((unsigned short*)Cout)[row * N + col] = f2bf(v);
        } else if (EPI == 1) {
          ((float*)Cout)[row * N + col] += v;
        } else if (EPI == 2) {
          ((float*)Cout)[row * N + col] = v;
        } else {
          float gpart = __shfl_xor(v, 1);
          if ((lq & 1) == 0) {
            float uval =
                v * (0.5f * gpart * (1.0f + erff(gpart * 0.70710678118654752f)));
            ((unsigned short*)Cout)[row * (N >> 1) + (col >> 1)] = f2bf(uval);
          }
        }
      }
    }
  }
}

extern "C" void kernel_launch(void* const* d_in, const int* in_sizes, int n_in,
                              void* d_out, int out_size, void* d_ws, size_t ws_size,
                              hipStream_t stream) {
  (void)in_sizes; (void)n_in; (void)out_size; (void)ws_size;
  const int* tokens   = (const int*)d_in[0];
  const float* tok_emb = (const float*)d_in[1];
  const float* pos_emb = (const float*)d_in[2];
  const float* dpb_w1 = (const float*)d_in[3];
  const float* dpb_b1 = (const float*)d_in[4];
  const float* dpb_w2 = (const float*)d_in[5];
  const float* dpb_b2 = (const float*)d_in[6];
  const float* dpb_w3 = (const float*)d_in[7];
  const float* dpb_b3 = (const float*)d_in[8];
  const float* ln1_g  = (const float*)d_in[9];
  const float* ln1_b  = (const float*)d_in[10];
  const float* Wqkv   = (const float*)d_in[11];
  const float* Wo     = (const float*)d_in[12];
  const float* ln2_g  = (const float*)d_in[13];
  const float* ln2_b  = (const float*)d_in[14];
  const float* Wff1   = (const float*)d_in[15];
  const float* Wff2   = (const float*)d_in[16];
  const float* lnf_g  = (const float*)d_in[17];
  const float* lnf_b  = (const float*)d_in[18];
  const float* Wlog   = (const float*)d_in[19];
  float* out = (float*)d_out;

  char* p = (char*)d_ws;
  auto carve = [&](size_t bytes) {
    char* q = p;
    p += (bytes + 255) & ~(size_t)255;
    return (void*)q;
  };
  unsigned short* WqkvT = (unsigned short*)carve((size_t)4 * 3072 * 1024 * 2);
  unsigned short* WoT   = (unsigned short*)carve((size_t)4 * 1024 * 1024 * 2);
  unsigned short* Wff1T = (unsigned short*)carve((size_t)4 * 5504 * 1024 * 2);
  unsigned short* Wff2T = (unsigned short*)carve((size_t)4 * 1024 * 2752 * 2);
  unsigned short* WlogT = (unsigned short*)carve((size_t)32000 * 1024 * 2);
  float*          x     = (float*)carve((size_t)2048 * 1024 * 4);
  unsigned short* hbuf  = (unsigned short*)carve((size_t)2048 * 1024 * 2);
  unsigned short* qkv   = (unsigned short*)carve((size_t)2048 * 3072 * 2);
  unsigned short* ao    = (unsigned short*)carve((size_t)2048 * 1024 * 2);
  unsigned short* ubuf  = (unsigned short*)carve((size_t)2048 * 2752 * 2);
  float*          tableT = (float*)carve((size_t)16 * 1024 * 4);

  // prep: embed(2048) + dpb(1024) + tiles(10176) = 13248 blocks
  k_prep<<<13248, 256, 0, stream>>>(
      tokens, tok_emb, pos_emb, x, dpb_w1, dpb_b1, dpb_w2, dpb_b2, dpb_w3,
      dpb_b3, tableT, Wqkv, WqkvT, Wo, WoT, Wff1, Wff1T, Wff2, Wff2T, Wlog, WlogT);

  for (int l = 0; l < 4; ++l) {
    k_ln4<<<512, 256, 0, stream>>>(x, ln1_g + l * 1024, ln1_b + l * 1024, hbuf);
    k_gemm<0, 64><<<dim3(32 * (3072 / 128)), 256, 0, stream>>>(
        hbuf, WqkvT + (long)l * 3072 * 1024, qkv, 3072, 1024, 32);
    k_attn_mfma<<<dim3(8, 16, 4), 256, 0, stream>>>(qkv, tableT, ao);
    k_gemm<1, 64><<<dim3(32 * (1024 / 128)), 256, 0, stream>>>(
        ao, WoT + (long)l * 1024 * 1024, x, 1024, 1024, 32);
    k_ln4<<<512, 256, 0, stream>>>(x, ln2_g + l * 1024, ln2_b + l * 1024, hbuf);
    k_gemm<3, 128><<<dim3(16 * (5504 / 128)), 256, 0, stream>>>(
        hbuf, Wff1T + (long)l * 5504 * 1024, ubuf, 5504, 1024, 16);
    k_gemm<1, 64><<<dim3(32 * (1024 / 128)), 256, 0, stream>>>(
        ubuf, Wff2T + (long)l * 1024 * 2752, x, 1024, 2752, 32);
  }
  k_ln4<<<512, 256, 0, stream>>>(x, lnf_g, lnf_b, hbuf);
  k_gemm<2, 128><<<dim3(16 * (32000 / 128)), 256, 0, stream>>>(
      hbuf, WlogT, out, 32000, 1024, 16);
}

// Round 16
// 1019.947 us; speedup vs baseline: 1.0365x; 1.0076x over previous
//
#include <hip/hip_runtime.h>
#include <cstdint>

#define DEV __device__ __forceinline__

typedef __attribute__((ext_vector_type(8))) short bf16x8;
typedef __attribute__((ext_vector_type(4))) short bf16x4;
typedef __attribute__((ext_vector_type(4))) float f32x4;
typedef __attribute__((ext_vector_type(8))) unsigned short u16x8;

DEV float bf2f(unsigned short u) { return __uint_as_float(((unsigned)u) << 16); }
DEV unsigned short f2bf(float f) {
  unsigned u = __float_as_uint(f);
  u += 0x7FFFu + ((u >> 16) & 1u);
  return (unsigned short)(u >> 16);
}

DEV void gload_lds16(const void* g, void* lds) {
  __builtin_amdgcn_global_load_lds(
      (const __attribute__((address_space(1))) unsigned int*)g,
      (__attribute__((address_space(3))) unsigned int*)lds, 16, 0, 0);
}

// ---------------- prep mega-kernel ----------------
// [0,2048) embed | [2048,3072) dpb | rest: weight fp32 (K,N) -> bf16 tiled
// B^T tile layout: [nt][kt][128 n][64 k], XOR swizzle pre-applied (element
// (r,k) at short-offset r*64 + ((k>>3)^(r&7))*8 + (k&7)).
// Tile stores are NONTEMPORAL: read only much later, so keep them out of
// L2/L3 and preserve read-side cache hits.
__global__ __launch_bounds__(256) void k_prep(
    const int* __restrict__ tokens, const float* __restrict__ tok_emb,
    const float* __restrict__ pos_emb, float* __restrict__ x,
    const float* __restrict__ w1, const float* __restrict__ b1,
    const float* __restrict__ w2, const float* __restrict__ b2,
    const float* __restrict__ w3, const float* __restrict__ b3,
    float* __restrict__ tableT,
    const float* __restrict__ Wqkv, unsigned short* __restrict__ WqkvT,
    const float* __restrict__ Wo, unsigned short* __restrict__ WoT,
    const float* __restrict__ Wff1, unsigned short* __restrict__ Wff1T,
    const float* __restrict__ Wff2, unsigned short* __restrict__ Wff2T,
    const float* __restrict__ Wlog, unsigned short* __restrict__ WlogT) {
  __shared__ unsigned short sm16[8192];  // 16KB: dst-tile image / dpb scratch
  int b = blockIdx.x, t = threadIdx.x;
  if (b < 2048) {  // ---- embed ----
    int tok = tokens[b];
    int c = t * 4;
    float4 a = *(const float4*)(tok_emb + (long)tok * 1024 + c);
    float4 p = *(const float4*)(pos_emb + (long)b * 1024 + c);
    float4 r;
    r.x = a.x + p.x; r.y = a.y + p.y; r.z = a.z + p.z; r.w = a.w + p.w;
    *(float4*)(x + (long)b * 1024 + c) = r;
    return;
  }
  b -= 2048;
  if (b < 1024) {  // ---- dpb: rel-position b; write tableT[h][1024] ----
    float* h1 = (float*)sm16;
    float* h2 = h1 + 512;
    float rf = (float)b;
    for (int c = t; c < 512; c += 256) {
      float v = rf * w1[c] + b1[c];
      h1[c] = v / (1.0f + __expf(-v));
    }
    __syncthreads();
    for (int c = t; c < 512; c += 256) {
      float acc = b2[c];
      for (int k2 = 0; k2 < 512; ++k2) acc = fmaf(h1[k2], w2[(long)k2 * 512 + c], acc);
      h2[c] = acc / (1.0f + __expf(-acc));
    }
    __syncthreads();
    if (t < 16) {
      float acc = b3[t];
      for (int k2 = 0; k2 < 512; ++k2) acc = fmaf(h2[k2], w3[k2 * 16 + t], acc);
      tableT[t * 1024 + b] = acc;
    }
    return;
  }
  b -= 1024;
  // ---- one dst tile (128 n x 64 k) per block ----
  const float* src; unsigned short* dst;
  int N, Kreal, nt, kt, mode;
  if (b < 1536) {  // qkv: 4 z x 24 nt x 16 kt
    int z = b / 384, r = b % 384;
    nt = r / 16; kt = r % 16; mode = 0; N = 3072; Kreal = 1024;
    src = Wqkv + (long)z * 1024 * 3072;
    dst = WqkvT + ((long)z * 384 + r) * 8192;
  } else if ((b -= 1536) < 512) {  // wo: 4 z x 8 x 16
    int z = b / 128, r = b % 128;
    nt = r / 16; kt = r % 16; mode = 0; N = 1024; Kreal = 1024;
    src = Wo + (long)z * 1024 * 1024;
    dst = WoT + ((long)z * 128 + r) * 8192;
  } else if ((b -= 512) < 2752) {  // ff1: 4 z x 43 x 16 (GLU interleave)
    int z = b / 688, r = b % 688;
    nt = r / 16; kt = r % 16; mode = 1; N = 5460; Kreal = 1024;
    src = Wff1 + (long)z * 1024 * 5460;
    dst = Wff1T + ((long)z * 688 + r) * 8192;
  } else if ((b -= 2752) < 1376) {  // ff2: 4 z x 8 x 43
    int z = b / 344, r = b % 344;
    nt = r / 43; kt = r % 43; mode = 0; N = 1024; Kreal = 2730;
    src = Wff2 + (long)z * 2730 * 1024;
    dst = Wff2T + ((long)z * 344 + r) * 8192;
  } else {  // wlog: 250 x 16
    b -= 1376;
    nt = b / 16; kt = b % 16; mode = 0; N = 32000; Kreal = 1024;
    src = Wlog;
    dst = WlogT + (long)b * 8192;
  }
  const int k0 = kt * 64;
  const int q = t & 31;   // n-quad: rows q*4 .. q*4+3
  const int kc = t >> 5;  // k-chunk: k = kc*8 + e
  u16x8 pa, pb, pc, pd;   // bf16 k-vectors for the 4 owned rows
  if (mode == 0) {
    const int nb = nt * 128 + q * 4;
    float4 v[8];
#pragma unroll
    for (int e = 0; e < 8; ++e) {
      int k = k0 + kc * 8 + e;
      int kcl = min(k, Kreal - 1);
      v[e] = *(const float4*)(src + (long)kcl * N + nb);
    }
    __builtin_amdgcn_sched_barrier(0);
#pragma unroll
    for (int e = 0; e < 8; ++e) {
      bool ok = (k0 + kc * 8 + e) < Kreal;
      pa[e] = ok ? f2bf(v[e].x) : (unsigned short)0;
      pb[e] = ok ? f2bf(v[e].y) : (unsigned short)0;
      pc[e] = ok ? f2bf(v[e].z) : (unsigned short)0;
      pd[e] = ok ? f2bf(v[e].w) : (unsigned short)0;
    }
  } else {
    const int f0 = nt * 64 + q * 2;
    const int f0c = min(f0, 2728);
    float2 av[8], gvv[8];
#pragma unroll
    for (int e = 0; e < 8; ++e) {
      const float* sr = src + (long)(k0 + kc * 8 + e) * 5460;
      av[e] = *(const float2*)(sr + f0c);
      gvv[e] = *(const float2*)(sr + 2730 + f0c);
    }
    __builtin_amdgcn_sched_barrier(0);
    const bool ok0 = f0 < 2730, ok1 = (f0 + 1) < 2730;
#pragma unroll
    for (int e = 0; e < 8; ++e) {
      pa[e] = ok0 ? f2bf(av[e].x) : (unsigned short)0;
      pb[e] = ok0 ? f2bf(gvv[e].x) : (unsigned short)0;
      pc[e] = ok1 ? f2bf(av[e].y) : (unsigned short)0;
      pd[e] = ok1 ? f2bf(gvv[e].y) : (unsigned short)0;
    }
  }
  {
    const int r0 = q * 4;
    *(u16x8*)&sm16[(r0 + 0) * 64 + ((kc ^ ((r0 + 0) & 7)) * 8)] = pa;
    *(u16x8*)&sm16[(r0 + 1) * 64 + ((kc ^ ((r0 + 1) & 7)) * 8)] = pb;
    *(u16x8*)&sm16[(r0 + 2) * 64 + ((kc ^ ((r0 + 2) & 7)) * 8)] = pc;
    *(u16x8*)&sm16[(r0 + 3) * 64 + ((kc ^ ((r0 + 3) & 7)) * 8)] = pd;
  }
  __syncthreads();
#pragma unroll
  for (int i2 = 0; i2 < 4; ++i2) {
    u16x8 val = *(const u16x8*)&sm16[i2 * 2048 + t * 8];
    __builtin_nontemporal_store(val, (u16x8*)(dst + i2 * 2048 + t * 8));
  }
}

// ---------------- layernorm: one wave per row, 4 rows/block ----------------
__global__ __launch_bounds__(256) void k_ln4(const float* __restrict__ x,
    const float* __restrict__ g, const float* __restrict__ b,
    unsigned short* __restrict__ out) {
  const int row = blockIdx.x * 4 + (threadIdx.x >> 6);
  const int l = threadIdx.x & 63;
  const float* xr = x + (long)row * 1024 + l * 16;
  float4 v[4];
#pragma unroll
  for (int e = 0; e < 4; ++e) v[e] = ((const float4*)xr)[e];
  float s = 0.0f;
#pragma unroll
  for (int e = 0; e < 4; ++e) s += v[e].x + v[e].y + v[e].z + v[e].w;
#pragma unroll
  for (int off = 32; off; off >>= 1) s += __shfl_xor(s, off);
  float mean = s * (1.0f / 1024.0f);
  float sq = 0.0f;
#pragma unroll
  for (int e = 0; e < 4; ++e) {
    float a0 = v[e].x - mean, a1 = v[e].y - mean, a2 = v[e].z - mean, a3 = v[e].w - mean;
    sq += a0 * a0 + a1 * a1 + a2 * a2 + a3 * a3;
  }
#pragma unroll
  for (int off = 32; off; off >>= 1) sq += __shfl_xor(sq, off);
  float inv = rsqrtf(sq * (1.0f / 1024.0f) + 1e-5f);
  const float* gr = g + l * 16;
  const float* br = b + l * 16;
  unsigned short* orow = out + (long)row * 1024 + l * 16;
#pragma unroll
  for (int e = 0; e < 4; ++e) {
    float4 gv = ((const float4*)gr)[e];
    float4 bv = ((const float4*)br)[e];
    ushort4 o;
    o.x = f2bf((v[e].x - mean) * inv * gv.x + bv.x);
    o.y = f2bf((v[e].y - mean) * inv * gv.y + bv.y);
    o.z = f2bf((v[e].z - mean) * inv * gv.z + bv.z);
    o.w = f2bf((v[e].w - mean) * inv * gv.w + bv.w);
    ((ushort4*)orow)[e] = o;
  }
}

// ---------------- MFMA flash local attention ----------------
__global__ __launch_bounds__(256, 2) void k_attn_mfma(
    const unsigned short* __restrict__ qkv, const float* __restrict__ tableT,
    unsigned short* __restrict__ o) {
  __shared__ unsigned short Ks[64 * 64];
  __shared__ unsigned short Vt[64 * 72];
  __shared__ unsigned short Ps[4][16 * 72];
  __shared__ float biasl[1024];
  const int qt = blockIdx.x, h = blockIdx.y, wi = blockIdx.z;
  const int iw0 = qt * 64;
  const int t = threadIdx.x;
  const int w = t >> 6, l = t & 63;
  const int lq = l & 15, lk = l >> 4;

  *(float4*)&biasl[t * 4] = *(const float4*)(tableT + h * 1024 + t * 4);

  const unsigned short* qp = qkv + (long)(wi * 512 + iw0 + w * 16 + lq) * 3072 + h * 64;
  bf16x8 qf0 = *(const bf16x8*)(qp + lk * 8);
  bf16x8 qf1 = *(const bf16x8*)(qp + 32 + lk * 8);

  f32x4 oacc[4] = {};
  float mrun[4] = {-3.0e38f, -3.0e38f, -3.0e38f, -3.0e38f};
  float srun[4] = {};

  const int kt0 = (wi == 0) ? 8 : qt;
  const int kt1 = qt + 8;
  for (int kt = kt0; kt <= kt1; ++kt) {
    const int ktbase = kt * 64;
    const long kgbase = (long)((wi - 1) * 512 + ktbase);
    __syncthreads();
    {
      const unsigned short* Kg = qkv + kgbase * 3072 + 1024 + h * 64;
#pragma unroll
      for (int s2 = 0; s2 < 2; ++s2) {
        int g = s2 * 4 + w;
        int row = g * 8 + (l >> 3);
        int gch = (l & 7) ^ (row & 7);
        gload_lds16(Kg + (long)row * 3072 + gch * 8, &Ks[g * 512]);
      }
    }
    {
      int kp = t & 31, dg = t >> 5;
      const unsigned short* Vg =
          qkv + (kgbase + 2 * kp) * 3072 + 2048 + h * 64 + dg * 8;
      bf16x8 a0 = *(const bf16x8*)Vg;
      bf16x8 a1 = *(const bf16x8*)(Vg + 3072);
#pragma unroll
      for (int e = 0; e < 8; ++e) {
        unsigned pack = ((unsigned)(unsigned short)a0[e]) |
                        (((unsigned)(unsigned short)a1[e]) << 16);
        *(unsigned*)&Vt[(dg * 8 + e) * 72 + 2 * kp] = pack;
      }
    }
    asm volatile("s_waitcnt vmcnt(0)" ::: "memory");
    __syncthreads();

    f32x4 sacc[4] = {};
#pragma unroll
    for (int ct = 0; ct < 4; ++ct) {
      int krow = ct * 16 + lq;
      bf16x8 kf0 = *(const bf16x8*)&Ks[krow * 64 + (((0 + lk) ^ (krow & 7)) * 8)];
      bf16x8 kf1 = *(const bf16x8*)&Ks[krow * 64 + (((4 + lk) ^ (krow & 7)) * 8)];
      sacc[ct] = __builtin_amdgcn_mfma_f32_16x16x32_bf16(qf0, kf0, sacc[ct], 0, 0, 0);
      sacc[ct] = __builtin_amdgcn_mfma_f32_16x16x32_bf16(qf1, kf1, sacc[ct], 0, 0, 0);
    }

#pragma unroll
    for (int r = 0; r < 4; ++r) {
      const int iw = iw0 + w * 16 + lk * 4 + r;
      float sc[4];
#pragma unroll
      for (int ct = 0; ct < 4; ++ct) {
        int jj = ktbase + ct * 16 + lq;
        int di = 512 + iw - jj;
        int dic = min(max(di, 0), 1023);
        bool allowed = (jj >= iw) && (jj <= iw + 512);
        float v = sacc[ct][r] * 0.125f + biasl[dic];
        sc[ct] = allowed ? v : -3.0e38f;
      }
      float mx = fmaxf(fmaxf(sc[0], sc[1]), fmaxf(sc[2], sc[3]));
      mx = fmaxf(mx, __shfl_xor(mx, 1));
      mx = fmaxf(mx, __shfl_xor(mx, 2));
      mx = fmaxf(mx, __shfl_xor(mx, 4));
      mx = fmaxf(mx, __shfl_xor(mx, 8));
      float mnew = fmaxf(mrun[r], mx);
      float f = __expf(mrun[r] - mnew);
      mrun[r] = mnew;
      float rs = 0.0f;
#pragma unroll
      for (int ct = 0; ct < 4; ++ct) {
        float pv = __expf(sc[ct] - mnew);
        rs += pv;
        Ps[w][(lk * 4 + r) * 72 + ct * 16 + lq] = f2bf(pv);
      }
      rs += __shfl_xor(rs, 1);
      rs += __shfl_xor(rs, 2);
      rs += __shfl_xor(rs, 4);
      rs += __shfl_xor(rs, 8);
      srun[r] = srun[r] * f + rs;
#pragma unroll
      for (int dt = 0; dt < 4; ++dt) oacc[dt][r] *= f;
    }
    asm volatile("s_waitcnt lgkmcnt(0)" ::: "memory");

#pragma unroll
    for (int ks = 0; ks < 2; ++ks) {
      bf16x4 pa0 = *(const bf16x4*)&Ps[w][lq * 72 + ks * 32 + lk * 8];
      bf16x4 pa1 = *(const bf16x4*)&Ps[w][lq * 72 + ks * 32 + lk * 8 + 4];
      bf16x8 pa = __builtin_shufflevector(pa0, pa1, 0, 1, 2, 3, 4, 5, 6, 7);
#pragma unroll
      for (int dt = 0; dt < 4; ++dt) {
        int drow = dt * 16 + lq;
        bf16x4 vb0 = *(const bf16x4*)&Vt[drow * 72 + ks * 32 + lk * 8];
        bf16x4 vb1 = *(const bf16x4*)&Vt[drow * 72 + ks * 32 + lk * 8 + 4];
        bf16x8 vb = __builtin_shufflevector(vb0, vb1, 0, 1, 2, 3, 4, 5, 6, 7);
        oacc[dt] = __builtin_amdgcn_mfma_f32_16x16x32_bf16(pa, vb, oacc[dt], 0, 0, 0);
      }
    }
  }

  unsigned short* ob =
      o + (long)(wi * 512 + iw0 + w * 16 + lk * 4) * 1024 + h * 64 + lq;
#pragma unroll
  for (int r = 0; r < 4; ++r) {
    float inv = 1.0f / srun[r];
#pragma unroll
    for (int dt = 0; dt < 4; ++dt)
      ob[(long)r * 1024 + dt * 16] = f2bf(oacc[dt][r] * inv);
  }
}

// ---------------- GEMM: C(M,N) = A(M,K) * B^T, B in tiled layout ----------
// Single-buffer (r8 structure — 3 blocks/CU wave-overlap beats explicit dbuf;
// r9/r12/r14 pipeline variants all regressed via occupancy loss).
// B: [nt][kt][128][64] swizzle-pre-applied tiles -> staging = linear copy.
// 1D grid, bm-fast + bijective XCD swizzle.
// EPI: 0 = store bf16, 1 = fp32 +=, 2 = store fp32 NONTEMPORAL (write-once
// logits stream must not evict A/B panels from L2/L3), 3 = fused GLU
template <int EPI, int BM>
__global__ __launch_bounds__(256, 2) void k_gemm(const unsigned short* __restrict__ A,
    const unsigned short* __restrict__ BTt, void* __restrict__ Cout,
    int N, int K, int nbm) {
  constexpr int MI = BM / 32;
  __shared__ unsigned short As[BM * 64];
  __shared__ unsigned short Bs[128 * 64];
  const int nwg = gridDim.x;
  const int orig = blockIdx.x;
  const int q8 = nwg >> 3, r8 = nwg & 7;
  const int xcd = orig & 7, i8 = orig >> 3;
  const int wgid = (xcd < r8 ? xcd * (q8 + 1) : r8 * (q8 + 1) + (xcd - r8) * q8) + i8;
  const int bm = wgid % nbm;
  const int bn = wgid / nbm;
  const int t = threadIdx.x;
  const int w = t >> 6, l = t & 63;
  const int wm = w >> 1, wn = w & 1;
  const int lrow = l >> 3, lch = l & 7;
  const int lq = l & 15, lk = l >> 4;
  f32x4 acc[MI][4] = {};
  const long arow0 = (long)bm * BM;
  const unsigned short* btile = BTt + (long)bn * (K >> 6) * 8192;
  for (int kt = 0; kt < K; kt += 64) {
    __syncthreads();
    const unsigned short* bsrc = btile + (long)(kt >> 6) * 8192 + l * 8;
#pragma unroll
    for (int s2 = 0; s2 < 4; ++s2) {
      int grp = s2 * 4 + w;
      gload_lds16(bsrc + grp * 512, &Bs[grp * 512]);
      if (s2 < MI) {
        int r = grp * 8 + lrow;
        int gch = lch ^ lrow;
        gload_lds16(A + (arow0 + r) * K + kt + gch * 8, &As[grp * 512]);
      }
    }
    asm volatile("s_waitcnt vmcnt(0)" ::: "memory");
    __syncthreads();
#pragma unroll
    for (int kk = 0; kk < 2; ++kk) {
      bf16x8 af[MI], bfr[4];
#pragma unroll
      for (int i = 0; i < MI; ++i) {
        int ra = wm * (BM / 2) + i * 16 + lq;
        af[i] = *(const bf16x8*)&As[ra * 64 + (((kk * 4 + lk) ^ (ra & 7)) * 8)];
      }
#pragma unroll
      for (int j = 0; j < 4; ++j) {
        int rb = wn * 64 + j * 16 + lq;
        bfr[j] = *(const bf16x8*)&Bs[rb * 64 + (((kk * 4 + lk) ^ (rb & 7)) * 8)];
      }
#pragma unroll
      for (int i = 0; i < MI; ++i)
#pragma unroll
        for (int j = 0; j < 4; ++j)
          acc[i][j] = __builtin_amdgcn_mfma_f32_16x16x32_bf16(af[i], bfr[j],
                                                              acc[i][j], 0, 0, 0);
    }
  }
  const int rbase = bm * BM + wm * (BM / 2) + lk * 4;
  const int cbase = bn * 128 + wn * 64 + lq;
#pragma unroll
  for (int i = 0; i < MI; ++i) {
#pragma unroll
    for (int j = 0; j < 4; ++j) {
#pragma unroll
      for (int r2 = 0; r2 < 4; ++r2) {
        long row = rbase + i * 16 + r2;
        long col = cbase + j * 16;
        float v = acc[i][j][r2];
        if (EPI == 0) {
          ((unsigned short*)Cout)[row * N + col] = f2bf(v);
        } else if (EPI == 1) {
          ((float*)Cout)[row * N + col] += v;
        } else if (EPI == 2) {
          __builtin_nontemporal_store(v, (float*)Cout + row * N + col);
        } else {
          float gpart = __shfl_xor(v, 1);
          if ((lq & 1) == 0) {
            float uval =
                v * (0.5f * gpart * (1.0f + erff(gpart * 0.70710678118654752f)));
            ((unsigned short*)Cout)[row * (N >> 1) + (col >> 1)] = f2bf(uval);
          }
        }
      }
    }
  }
}

extern "C" void kernel_launch(void* const* d_in, const int* in_sizes, int n_in,
                              void* d_out, int out_size, void* d_ws, size_t ws_size,
                              hipStream_t stream) {
  (void)in_sizes; (void)n_in; (void)out_size; (void)ws_size;
  const int* tokens   = (const int*)d_in[0];
  const float* tok_emb = (const float*)d_in[1];
  const float* pos_emb = (const float*)d_in[2];
  const float* dpb_w1 = (const float*)d_in[3];
  const float* dpb_b1 = (const float*)d_in[4];
  const float* dpb_w2 = (const float*)d_in[5];
  const float* dpb_b2 = (const float*)d_in[6];
  const float* dpb_w3 = (const float*)d_in[7];
  const float* dpb_b3 = (const float*)d_in[8];
  const float* ln1_g  = (const float*)d_in[9];
  const float* ln1_b  = (const float*)d_in[10];
  const float* Wqkv   = (const float*)d_in[11];
  const float* Wo     = (const float*)d_in[12];
  const float* ln2_g  = (const float*)d_in[13];
  const float* ln2_b  = (const float*)d_in[14];
  const float* Wff1   = (const float*)d_in[15];
  const float* Wff2   = (const float*)d_in[16];
  const float* lnf_g  = (const float*)d_in[17];
  const float* lnf_b  = (const float*)d_in[18];
  const float* Wlog   = (const float*)d_in[19];
  float* out = (float*)d_out;

  char* p = (char*)d_ws;
  auto carve = [&](size_t bytes) {
    char* q = p;
    p += (bytes + 255) & ~(size_t)255;
    return (void*)q;
  };
  unsigned short* WqkvT = (unsigned short*)carve((size_t)4 * 3072 * 1024 * 2);
  unsigned short* WoT   = (unsigned short*)carve((size_t)4 * 1024 * 1024 * 2);
  unsigned short* Wff1T = (unsigned short*)carve((size_t)4 * 5504 * 1024 * 2);
  unsigned short* Wff2T = (unsigned short*)carve((size_t)4 * 1024 * 2752 * 2);
  unsigned short* WlogT = (unsigned short*)carve((size_t)32000 * 1024 * 2);
  float*          x     = (float*)carve((size_t)2048 * 1024 * 4);
  unsigned short* hbuf  = (unsigned short*)carve((size_t)2048 * 1024 * 2);
  unsigned short* qkv   = (unsigned short*)carve((size_t)2048 * 3072 * 2);
  unsigned short* ao    = (unsigned short*)carve((size_t)2048 * 1024 * 2);
  unsigned short* ubuf  = (unsigned short*)carve((size_t)2048 * 2752 * 2);
  float*          tableT = (float*)carve((size_t)16 * 1024 * 4);

  // prep: embed(2048) + dpb(1024) + tiles(10176) = 13248 blocks
  k_prep<<<13248, 256, 0, stream>>>(
      tokens, tok_emb, pos_emb, x, dpb_w1, dpb_b1, dpb_w2, dpb_b2, dpb_w3,
      dpb_b3, tableT, Wqkv, WqkvT, Wo, WoT, Wff1, Wff1T, Wff2, Wff2T, Wlog, WlogT);

  for (int l = 0; l < 4; ++l) {
    k_ln4<<<512, 256, 0, stream>>>(x, ln1_g + l * 1024, ln1_b + l * 1024, hbuf);
    k_gemm<0, 64><<<dim3(32 * (3072 / 128)), 256, 0, stream>>>(
        hbuf, WqkvT + (long)l * 3072 * 1024, qkv, 3072, 1024, 32);
    k_attn_mfma<<<dim3(8, 16, 4), 256, 0, stream>>>(qkv, tableT, ao);
    k_gemm<1, 64><<<dim3(32 * (1024 / 128)), 256, 0, stream>>>(
        ao, WoT + (long)l * 1024 * 1024, x, 1024, 1024, 32);
    k_ln4<<<512, 256, 0, stream>>>(x, ln2_g + l * 1024, ln2_b + l * 1024, hbuf);
    k_gemm<3, 128><<<dim3(16 * (5504 / 128)), 256, 0, stream>>>(
        hbuf, Wff1T + (long)l * 5504 * 1024, ubuf, 5504, 1024, 16);
    k_gemm<1, 64><<<dim3(32 * (1024 / 128)), 256, 0, stream>>>(
        ubuf, Wff2T + (long)l * 1024 * 2752, x, 1024, 2752, 32);
  }
  k_ln4<<<512, 256, 0, stream>>>(x, lnf_g, lnf_b, hbuf);
  k_gemm<2, 128><<<dim3(16 * (32000 / 128)), 256, 0, stream>>>(
      hbuf, WlogT, out, 32000, 1024, 16);
}